// Round 3
// baseline (1637.162 us; speedup 1.0000x reference)
//
#include <hip/hip_runtime.h>
#include <hip/hip_bf16.h>

// GCN: gcn_norm -> conv1(relu) -> conv2(relu) -> mean-pool -> MLP head.
// R3: bucket-partitioned edge processing. Edges are radix-partitioned by
// destination bucket (128 nodes) into contiguous 8B records, then each
// bucket is aggregated in a 32KB LDS accumulator (no CSR, no per-edge
// global atomics). dinv folded into GEMM epilogue (h' = dinv * X@W).

#define DIMH 64
#define BSH 7                 // bucket shift: 128 nodes per bucket
#define BSZ 128
#define NBUCK_MAX 1024
#define EPB 8192              // edges per partition block

// ---- pass 1: global bucket histogram (LDS-staged) ----
__global__ __launch_bounds__(512) void k_hist(const int* __restrict__ col,
                                              int* __restrict__ cntB, int E, int nbuck) {
    __shared__ int h[NBUCK_MAX];
    for (int i = threadIdx.x; i < nbuck; i += 512) h[i] = 0;
    __syncthreads();
    int ebeg = blockIdx.x * EPB;
    int eend = min(ebeg + EPB, E);
    for (int e = ebeg + threadIdx.x; e < eend; e += 512)
        atomicAdd(&h[col[e] >> BSH], 1);
    __syncthreads();
    for (int i = threadIdx.x; i < nbuck; i += 512)
        if (h[i]) atomicAdd(&cntB[i], h[i]);
}

// ---- scan bucket counts -> base[nbuck+1], cursor init ----
__global__ __launch_bounds__(1024) void k_scan(const int* __restrict__ cntB,
                                               int* __restrict__ base,
                                               int* __restrict__ cursor, int nbuck, int E) {
    __shared__ int s[1024];
    int tid = threadIdx.x;
    int v = tid < nbuck ? cntB[tid] : 0;
    s[tid] = v;
    __syncthreads();
    for (int o = 1; o < 1024; o <<= 1) {
        int t = tid >= o ? s[tid - o] : 0;
        __syncthreads();
        s[tid] += t;
        __syncthreads();
    }
    if (tid < nbuck) {
        int ex = s[tid] - v;
        base[tid] = ex;
        cursor[tid] = ex;
    }
    if (tid == 0) base[nbuck] = E;
}

// ---- pass 2: scatter edges into bucket-contiguous packed records ----
// record: [63:32]=w fp32 bits, [31:8]=src, [7:0]=c_local
__global__ __launch_bounds__(512) void k_scatter(const int* __restrict__ row,
                                                 const int* __restrict__ col,
                                                 const float* __restrict__ ew,
                                                 int* __restrict__ cursor,
                                                 unsigned long long* __restrict__ part,
                                                 int E, int nbuck) {
    __shared__ int h[NBUCK_MAX];
    __shared__ int h2[NBUCK_MAX];
    __shared__ int st[NBUCK_MAX];
    for (int i = threadIdx.x; i < nbuck; i += 512) { h[i] = 0; h2[i] = 0; }
    __syncthreads();
    int ebeg = blockIdx.x * EPB;
    int eend = min(ebeg + EPB, E);
    for (int e = ebeg + threadIdx.x; e < eend; e += 512)
        atomicAdd(&h[col[e] >> BSH], 1);
    __syncthreads();
    for (int i = threadIdx.x; i < nbuck; i += 512) {
        int c = h[i];
        st[i] = c ? atomicAdd(&cursor[i], c) : 0;
    }
    __syncthreads();
    for (int e = ebeg + threadIdx.x; e < eend; e += 512) {
        int c = col[e];
        int b = c >> BSH;
        int r = atomicAdd(&h2[b], 1);
        unsigned long long rec =
            ((unsigned long long)__float_as_uint(ew[e]) << 32) |
            ((unsigned long long)(unsigned)row[e] << 8) |
            (unsigned)(c & (BSZ - 1));
        part[st[b] + r] = rec;
    }
}

// ---- per-bucket weighted degree -> dinv ----
__global__ __launch_bounds__(256) void k_degB(const unsigned long long* __restrict__ part,
                                              const int* __restrict__ base,
                                              float* __restrict__ dinv, int N) {
    __shared__ float dg[BSZ];
    int b = blockIdx.x;
    int nb0 = b << BSH;
    int nn = min(BSZ, N - nb0);
    if (threadIdx.x < BSZ) dg[threadIdx.x] = 1.0f;  // self-loop weight
    __syncthreads();
    int ebeg = base[b], eend = base[b + 1];
    for (int e = ebeg + threadIdx.x; e < eend; e += 256) {
        unsigned long long rec = part[e];
        float w = __uint_as_float((unsigned)(rec >> 32));
        atomicAdd(&dg[(int)(rec & (BSZ - 1))], w);
    }
    __syncthreads();
    if (threadIdx.x < nn) {
        float d = dg[threadIdx.x];
        dinv[nb0 + threadIdx.x] = d > 0.f ? rsqrtf(d) : 0.f;
    }
}

// ---- Y[i,:] = dinv[i] * (X[i,:] @ W) ----
template <int K, int H>
__global__ __launch_bounds__(256) void k_gemm_s(const float* __restrict__ X,
                                                const float* __restrict__ W,
                                                const float* __restrict__ dinv,
                                                float* __restrict__ Y, int n) {
    __shared__ float Ws[K * H];
    int tid = threadIdx.x;
    for (int i = tid * 4; i < K * H; i += 256 * 4)
        *(float4*)&Ws[i] = *(const float4*)&W[i];
    __syncthreads();

    constexpr int TPR = H / 16;
    constexpr int RPT = 4;
    int c0 = (tid % TPR) * 16;
    int rg = tid / TPR;
    int row0 = blockIdx.x * ((256 / TPR) * RPT) + rg * RPT;
    if (row0 >= n) return;

    float acc[RPT][16];
#pragma unroll
    for (int r = 0; r < RPT; r++)
#pragma unroll
        for (int j = 0; j < 16; j++) acc[r][j] = 0.f;

    int ridx[RPT];
#pragma unroll
    for (int r = 0; r < RPT; r++) ridx[r] = min(row0 + r, n - 1);

    for (int k = 0; k < K; k += 4) {
        float4 xv[RPT];
#pragma unroll
        for (int r = 0; r < RPT; r++)
            xv[r] = *(const float4*)&X[(size_t)ridx[r] * K + k];
#pragma unroll
        for (int kk = 0; kk < 4; kk++) {
            const float* wp = &Ws[(k + kk) * H + c0];
            float w[16];
#pragma unroll
            for (int j = 0; j < 16; j++) w[j] = wp[j];
#pragma unroll
            for (int r = 0; r < RPT; r++) {
                float xs = (&xv[r].x)[kk];
#pragma unroll
                for (int j = 0; j < 16; j++) acc[r][j] += xs * w[j];
            }
        }
    }
#pragma unroll
    for (int r = 0; r < RPT; r++) {
        if (row0 + r < n) {
            float di = dinv[row0 + r];
            float* yr = Y + (size_t)(row0 + r) * H + c0;
#pragma unroll
            for (int j = 0; j < 16; j += 4) {
                float4 o = {di * acc[r][j], di * acc[r][j + 1],
                            di * acc[r][j + 2], di * acc[r][j + 3]};
                *(float4*)&yr[j] = o;
            }
        }
    }
}

// ---- per-bucket aggregation in LDS ----
// Hin is h' = dinv*h. out = relu(dinv[c]*(h'[c] + sum w*h'[src]) + bias)
__global__ __launch_bounds__(512) void k_aggB(const float* __restrict__ Hin,
                                              const unsigned long long* __restrict__ part,
                                              const int* __restrict__ base,
                                              const float* __restrict__ dinv,
                                              const float* __restrict__ bias,
                                              float* __restrict__ Hout, int N) {
    __shared__ float acc[BSZ * DIMH];  // 32 KB
    int b = blockIdx.x;
    int nb0 = b << BSH;
    int nn = min(BSZ, N - nb0);
    int tid = threadIdx.x;
    // init acc with self term h'[c] (dense, vectorized)
    {
        const float4* src4 = (const float4*)(Hin + (size_t)nb0 * DIMH);
        float4* acc4 = (float4*)acc;
        for (int i = tid; i < nn * (DIMH / 4); i += 512) acc4[i] = src4[i];
    }
    __syncthreads();
    int lane = tid & 63;
    int wv = tid >> 6;
    int ebeg = base[b], eend = base[b + 1];
    for (int e = ebeg + wv; e < eend; e += 8) {
        unsigned long long rec = part[e];
        float w = __uint_as_float((unsigned)(rec >> 32));
        int src = (int)((rec >> 8) & 0xFFFFFF);
        int cl = (int)(rec & (BSZ - 1));
        atomicAdd(&acc[cl * DIMH + lane], w * Hin[(size_t)src * DIMH + lane]);
    }
    __syncthreads();
    for (int i = wv; i < nn; i += 8) {
        float v = dinv[nb0 + i] * acc[i * DIMH + lane] + bias[lane];
        Hout[(size_t)(nb0 + i) * DIMH + lane] = v > 0.f ? v : 0.f;
    }
}

// ---- mean-pool (b sorted): per-wave chunk accumulate, flush on change ----
__global__ __launch_bounds__(256) void k_pool(const float* __restrict__ Hin,
                                              const int* __restrict__ b,
                                              float* __restrict__ sums,
                                              float* __restrict__ cntG, int n) {
    const int CHUNK = 64;
    int lane = threadIdx.x & 63;
    int wave = threadIdx.x >> 6;
    int start = (blockIdx.x * 4 + wave) * CHUNK;
    if (start >= n) return;
    int end = min(start + CHUNK, n);
    float acc = 0.f;
    int g_cur = b[start];
    int cnt_local = 0;
    for (int i = start; i < end; i++) {
        int g = b[i];
        if (g != g_cur) {
            atomicAdd(&sums[g_cur * DIMH + lane], acc);
            if (lane == 0) atomicAdd(&cntG[g_cur], (float)cnt_local);
            acc = 0.f;
            cnt_local = 0;
            g_cur = g;
        }
        acc += Hin[(size_t)i * DIMH + lane];
        cnt_local++;
    }
    atomicAdd(&sums[g_cur * DIMH + lane], acc);
    if (lane == 0) atomicAdd(&cntG[g_cur], (float)cnt_local);
}

// ---- head MLP ----
__global__ __launch_bounds__(64) void k_mlp(const float* __restrict__ sums,
                                            const float* __restrict__ cntG,
                                            const float* __restrict__ Wm1,
                                            const float* __restrict__ bm1,
                                            const float* __restrict__ Wm2,
                                            const float* __restrict__ bm2,
                                            float* __restrict__ out, int G) {
    int g = threadIdx.x;
    if (g >= G) return;
    float c = cntG[g];
    float inv = 1.f / (c > 1.f ? c : 1.f);
    float pooled[DIMH];
#pragma unroll
    for (int k = 0; k < DIMH; k++) pooled[k] = sums[g * DIMH + k] * inv;
    float o = 0.f;
    for (int j = 0; j < 32; j++) {
        float t = bm1[j];
#pragma unroll
        for (int k = 0; k < DIMH; k++) t += pooled[k] * Wm1[k * 32 + j];
        t = t > 0.f ? t : 0.f;
        o += t * Wm2[j];
    }
    out[g] = o + bm2[0];
}

// ============================== launch ==============================

extern "C" void kernel_launch(void* const* d_in, const int* in_sizes, int n_in,
                              void* d_out, int out_size, void* d_ws, size_t ws_size,
                              hipStream_t stream) {
    const float* x   = (const float*)d_in[0];
    const int*   ei  = (const int*)d_in[1];
    const float* ew  = (const float*)d_in[2];
    const int*   bvec= (const int*)d_in[3];
    const float* W1  = (const float*)d_in[4];
    const float* b1  = (const float*)d_in[5];
    const float* W2  = (const float*)d_in[6];
    const float* b2  = (const float*)d_in[7];
    const float* Wm1 = (const float*)d_in[8];
    const float* bm1 = (const float*)d_in[9];
    const float* Wm2 = (const float*)d_in[10];
    const float* bm2 = (const float*)d_in[11];
    float* out = (float*)d_out;

    const int E = in_sizes[2];
    const int N = in_sizes[3];
    const int G = out_size;
    const int* row = ei;
    const int* col = ei + E;
    const int nbuck = (N + BSZ - 1) >> BSH;   // 782 for N=100000 (<=1024)

    char* p = (char*)d_ws;
    auto alloc = [&](size_t bytes) {
        void* r = (void*)p;
        p += (bytes + 255) & ~(size_t)255;
        return r;
    };

    unsigned long long* part = (unsigned long long*)alloc((size_t)E * 8);
    int*   cntB   = (int*)alloc((size_t)nbuck * 4);
    int*   base   = (int*)alloc((size_t)(nbuck + 1) * 4);
    int*   cursor = (int*)alloc((size_t)nbuck * 4);
    float* dinv   = (float*)alloc((size_t)N * 4);
    float* hA     = (float*)alloc((size_t)N * DIMH * 4);
    float* hB     = (float*)alloc((size_t)N * DIMH * 4);
    float* sums   = (float*)alloc((size_t)(G * DIMH + G) * 4);
    float* cntG   = sums + G * DIMH;

    hipMemsetAsync(cntB, 0, (size_t)nbuck * 4, stream);
    hipMemsetAsync(sums, 0, (size_t)(G * DIMH + G) * 4, stream);

    const int PB = (E + EPB - 1) / EPB;       // partition blocks (196)

    // 1. partition edges by destination bucket
    k_hist<<<PB, 512, 0, stream>>>(col, cntB, E, nbuck);
    k_scan<<<1, 1024, 0, stream>>>(cntB, base, cursor, nbuck, E);
    k_scatter<<<PB, 512, 0, stream>>>(row, col, ew, cursor, part, E, nbuck);
    k_degB<<<nbuck, 256, 0, stream>>>(part, base, dinv, N);

    // 2. conv1
    k_gemm_s<128, DIMH><<<(N + 255) / 256, 256, 0, stream>>>(x, W1, dinv, hA, N);
    k_aggB<<<nbuck, 512, 0, stream>>>(hA, part, base, dinv, b1, hB, N);

    // 3. conv2
    k_gemm_s<DIMH, DIMH><<<(N + 255) / 256, 256, 0, stream>>>(hB, W2, dinv, hA, N);
    k_aggB<<<nbuck, 512, 0, stream>>>(hA, part, base, dinv, b2, hB, N);

    // 4. pool + head
    k_pool<<<(N + 255) / 256, 256, 0, stream>>>(hB, bvec, sums, cntG, N);
    k_mlp<<<1, 64, 0, stream>>>(sums, cntG, Wm1, bm1, Wm2, bm2, out, G);
}

// Round 4
// 398.841 us; speedup vs baseline: 4.1048x; 4.1048x over previous
//
#include <hip/hip_runtime.h>
#include <hip/hip_bf16.h>

// GCN: gcn_norm -> conv1(relu) -> conv2(relu) -> mean-pool -> MLP head.
// R4: bucket radix partition (cheap, proven in R3) + within-bucket counting
// sort -> exact node-sorted CSR. Aggregation reverts to the proven R2 form:
// wave-per-node, register accumulation, now 8-deep independent gathers.
// No float atomics anywhere. dinv folded into GEMM epilogue (h' = dinv*X@W).

#define DIMH 64
#define BSH 7                 // 128 nodes per bucket
#define BSZ 128
#define NBUCK_MAX 1024
#define EPB 8192              // edges per partition block

// ---- pass 1: global bucket histogram (LDS-staged, int atomics) ----
__global__ __launch_bounds__(512) void k_hist(const int* __restrict__ col,
                                              int* __restrict__ cntB, int E, int nbuck) {
    __shared__ int h[NBUCK_MAX];
    for (int i = threadIdx.x; i < nbuck; i += 512) h[i] = 0;
    __syncthreads();
    int ebeg = blockIdx.x * EPB;
    int eend = min(ebeg + EPB, E);
    for (int e = ebeg + threadIdx.x; e < eend; e += 512)
        atomicAdd(&h[col[e] >> BSH], 1);
    __syncthreads();
    for (int i = threadIdx.x; i < nbuck; i += 512)
        if (h[i]) atomicAdd(&cntB[i], h[i]);
}

// ---- scan bucket counts -> base[nbuck+1], cursor init ----
__global__ __launch_bounds__(1024) void k_scan(const int* __restrict__ cntB,
                                               int* __restrict__ base,
                                               int* __restrict__ cursor, int nbuck, int E) {
    __shared__ int s[1024];
    int tid = threadIdx.x;
    int v = tid < nbuck ? cntB[tid] : 0;
    s[tid] = v;
    __syncthreads();
    for (int o = 1; o < 1024; o <<= 1) {
        int t = tid >= o ? s[tid - o] : 0;
        __syncthreads();
        s[tid] += t;
        __syncthreads();
    }
    if (tid < nbuck) {
        int ex = s[tid] - v;
        base[tid] = ex;
        cursor[tid] = ex;
    }
    if (tid == 0) base[nbuck] = E;
}

// ---- pass 2: scatter edges into bucket-contiguous packed records ----
// record: [63:32]=w fp32 bits, [31:8]=src, [7:0]=c_local
__global__ __launch_bounds__(512) void k_scatter(const int* __restrict__ row,
                                                 const int* __restrict__ col,
                                                 const float* __restrict__ ew,
                                                 int* __restrict__ cursor,
                                                 unsigned long long* __restrict__ part,
                                                 int E, int nbuck) {
    __shared__ int h[NBUCK_MAX];
    __shared__ int h2[NBUCK_MAX];
    __shared__ int st[NBUCK_MAX];
    for (int i = threadIdx.x; i < nbuck; i += 512) { h[i] = 0; h2[i] = 0; }
    __syncthreads();
    int ebeg = blockIdx.x * EPB;
    int eend = min(ebeg + EPB, E);
    for (int e = ebeg + threadIdx.x; e < eend; e += 512)
        atomicAdd(&h[col[e] >> BSH], 1);
    __syncthreads();
    for (int i = threadIdx.x; i < nbuck; i += 512) {
        int c = h[i];
        st[i] = c ? atomicAdd(&cursor[i], c) : 0;
    }
    __syncthreads();
    for (int e = ebeg + threadIdx.x; e < eend; e += 512) {
        int c = col[e];
        int b = c >> BSH;
        int r = atomicAdd(&h2[b], 1);
        unsigned long long rec =
            ((unsigned long long)__float_as_uint(ew[e]) << 32) |
            ((unsigned long long)(unsigned)row[e] << 8) |
            (unsigned)(c & (BSZ - 1));
        part[st[b] + r] = rec;
    }
}

// ---- pass 3: within-bucket counting sort -> node-sorted CSR + row_ptr + dinv ----
__global__ __launch_bounds__(256) void k_sortB(const unsigned long long* __restrict__ part,
                                               const int* __restrict__ base,
                                               int2* __restrict__ csr,
                                               int* __restrict__ row_ptr,
                                               float* __restrict__ dinv, int N, int E) {
    __shared__ int cnt[BSZ];
    __shared__ int scn[BSZ];
    __shared__ int cur[BSZ];
    int b = blockIdx.x;
    int nb0 = b << BSH;
    int nn = min(BSZ, N - nb0);
    int tid = threadIdx.x;
    if (tid < BSZ) cnt[tid] = 0;
    __syncthreads();
    int ebeg = base[b], eend = base[b + 1];
    for (int e = ebeg + tid; e < eend; e += 256)
        atomicAdd(&cnt[(int)(part[e] & (BSZ - 1))], 1);
    __syncthreads();
    if (tid < BSZ) scn[tid] = cnt[tid];
    __syncthreads();
    for (int o = 1; o < BSZ; o <<= 1) {
        int t = 0;
        if (tid >= o && tid < BSZ) t = scn[tid - o];
        __syncthreads();
        if (tid >= o && tid < BSZ) scn[tid] += t;
        __syncthreads();
    }
    if (tid < BSZ) {
        int ex = scn[tid] - cnt[tid];  // exclusive within bucket
        cur[tid] = ex;
        if (tid < nn) row_ptr[nb0 + tid] = ebeg + ex;
    }
    if (nb0 + nn == N && tid == 0) row_ptr[N] = E;
    __syncthreads();
    for (int e = ebeg + tid; e < eend; e += 256) {
        unsigned long long rec = part[e];
        int cl = (int)(rec & (BSZ - 1));
        int slot = atomicAdd(&cur[cl], 1);
        csr[ebeg + slot] = make_int2((int)((rec >> 8) & 0xFFFFFF),
                                     (int)(unsigned)(rec >> 32));
    }
    __syncthreads();
    if (tid < nn) {
        int s0 = ebeg + (scn[tid] - cnt[tid]);
        int c = cnt[tid];
        float s = 1.0f;  // self-loop weight
        for (int k = 0; k < c; k++) s += __int_as_float(csr[s0 + k].y);
        dinv[nb0 + tid] = rsqrtf(s);
    }
}

// ---- Y[i,:] = dinv[i] * (X[i,:] @ W) ----
template <int K, int H>
__global__ __launch_bounds__(256) void k_gemm_s(const float* __restrict__ X,
                                                const float* __restrict__ W,
                                                const float* __restrict__ dinv,
                                                float* __restrict__ Y, int n) {
    __shared__ float Ws[K * H];
    int tid = threadIdx.x;
    for (int i = tid * 4; i < K * H; i += 256 * 4)
        *(float4*)&Ws[i] = *(const float4*)&W[i];
    __syncthreads();

    constexpr int TPR = H / 16;
    constexpr int RPT = 4;
    int c0 = (tid % TPR) * 16;
    int rg = tid / TPR;
    int row0 = blockIdx.x * ((256 / TPR) * RPT) + rg * RPT;
    if (row0 >= n) return;

    float acc[RPT][16];
#pragma unroll
    for (int r = 0; r < RPT; r++)
#pragma unroll
        for (int j = 0; j < 16; j++) acc[r][j] = 0.f;

    int ridx[RPT];
#pragma unroll
    for (int r = 0; r < RPT; r++) ridx[r] = min(row0 + r, n - 1);

    for (int k = 0; k < K; k += 4) {
        float4 xv[RPT];
#pragma unroll
        for (int r = 0; r < RPT; r++)
            xv[r] = *(const float4*)&X[(size_t)ridx[r] * K + k];
#pragma unroll
        for (int kk = 0; kk < 4; kk++) {
            const float* wp = &Ws[(k + kk) * H + c0];
            float w[16];
#pragma unroll
            for (int j = 0; j < 16; j++) w[j] = wp[j];
#pragma unroll
            for (int r = 0; r < RPT; r++) {
                float xs = (&xv[r].x)[kk];
#pragma unroll
                for (int j = 0; j < 16; j++) acc[r][j] += xs * w[j];
            }
        }
    }
#pragma unroll
    for (int r = 0; r < RPT; r++) {
        if (row0 + r < n) {
            float di = dinv[row0 + r];
            float* yr = Y + (size_t)(row0 + r) * H + c0;
#pragma unroll
            for (int j = 0; j < 16; j += 4) {
                float4 o = {di * acc[r][j], di * acc[r][j + 1],
                            di * acc[r][j + 2], di * acc[r][j + 3]};
                *(float4*)&yr[j] = o;
            }
        }
    }
}

// ---- aggregation: wave-per-node, register acc, 8-deep independent gathers ----
// Hin is h' = dinv*h. out = relu(dinv[c]*(h'[c] + sum w*h'[src]) + bias)
__global__ __launch_bounds__(256) void k_aggN(const float* __restrict__ Hin,
                                              const int* __restrict__ row_ptr,
                                              const int2* __restrict__ csr,
                                              const float* __restrict__ dinv,
                                              const float* __restrict__ bias,
                                              float* __restrict__ Hout, int n) {
    int lane = threadIdx.x & 63;
    int wv = threadIdx.x >> 6;
    int node = blockIdx.x * 4 + wv;
    if (node >= n) return;
    int p = row_ptr[node];
    int p1 = row_ptr[node + 1];
    float acc = Hin[(size_t)node * DIMH + lane];  // self term h'[c]
    for (; p + 8 <= p1; p += 8) {
        int2 e0 = csr[p];
        int2 e1 = csr[p + 1];
        int2 e2 = csr[p + 2];
        int2 e3 = csr[p + 3];
        int2 e4 = csr[p + 4];
        int2 e5 = csr[p + 5];
        int2 e6 = csr[p + 6];
        int2 e7 = csr[p + 7];
        float h0 = Hin[(size_t)e0.x * DIMH + lane];
        float h1 = Hin[(size_t)e1.x * DIMH + lane];
        float h2 = Hin[(size_t)e2.x * DIMH + lane];
        float h3 = Hin[(size_t)e3.x * DIMH + lane];
        float h4 = Hin[(size_t)e4.x * DIMH + lane];
        float h5 = Hin[(size_t)e5.x * DIMH + lane];
        float h6 = Hin[(size_t)e6.x * DIMH + lane];
        float h7 = Hin[(size_t)e7.x * DIMH + lane];
        acc += __int_as_float(e0.y) * h0;
        acc += __int_as_float(e1.y) * h1;
        acc += __int_as_float(e2.y) * h2;
        acc += __int_as_float(e3.y) * h3;
        acc += __int_as_float(e4.y) * h4;
        acc += __int_as_float(e5.y) * h5;
        acc += __int_as_float(e6.y) * h6;
        acc += __int_as_float(e7.y) * h7;
    }
    for (; p + 2 <= p1; p += 2) {
        int2 e0 = csr[p];
        int2 e1 = csr[p + 1];
        float h0 = Hin[(size_t)e0.x * DIMH + lane];
        float h1 = Hin[(size_t)e1.x * DIMH + lane];
        acc += __int_as_float(e0.y) * h0;
        acc += __int_as_float(e1.y) * h1;
    }
    if (p < p1) {
        int2 e0 = csr[p];
        acc += __int_as_float(e0.y) * Hin[(size_t)e0.x * DIMH + lane];
    }
    float v = dinv[node] * acc + bias[lane];
    Hout[(size_t)node * DIMH + lane] = v > 0.f ? v : 0.f;
}

// ---- mean-pool (b sorted): per-wave chunk accumulate, flush on change ----
__global__ __launch_bounds__(256) void k_pool(const float* __restrict__ Hin,
                                              const int* __restrict__ b,
                                              float* __restrict__ sums,
                                              float* __restrict__ cntG, int n) {
    const int CHUNK = 64;
    int lane = threadIdx.x & 63;
    int wave = threadIdx.x >> 6;
    int start = (blockIdx.x * 4 + wave) * CHUNK;
    if (start >= n) return;
    int end = min(start + CHUNK, n);
    float acc = 0.f;
    int g_cur = b[start];
    int cnt_local = 0;
    for (int i = start; i < end; i++) {
        int g = b[i];
        if (g != g_cur) {
            atomicAdd(&sums[g_cur * DIMH + lane], acc);
            if (lane == 0) atomicAdd(&cntG[g_cur], (float)cnt_local);
            acc = 0.f;
            cnt_local = 0;
            g_cur = g;
        }
        acc += Hin[(size_t)i * DIMH + lane];
        cnt_local++;
    }
    atomicAdd(&sums[g_cur * DIMH + lane], acc);
    if (lane == 0) atomicAdd(&cntG[g_cur], (float)cnt_local);
}

// ---- head MLP ----
__global__ __launch_bounds__(64) void k_mlp(const float* __restrict__ sums,
                                            const float* __restrict__ cntG,
                                            const float* __restrict__ Wm1,
                                            const float* __restrict__ bm1,
                                            const float* __restrict__ Wm2,
                                            const float* __restrict__ bm2,
                                            float* __restrict__ out, int G) {
    int g = threadIdx.x;
    if (g >= G) return;
    float c = cntG[g];
    float inv = 1.f / (c > 1.f ? c : 1.f);
    float pooled[DIMH];
#pragma unroll
    for (int k = 0; k < DIMH; k++) pooled[k] = sums[g * DIMH + k] * inv;
    float o = 0.f;
    for (int j = 0; j < 32; j++) {
        float t = bm1[j];
#pragma unroll
        for (int k = 0; k < DIMH; k++) t += pooled[k] * Wm1[k * 32 + j];
        t = t > 0.f ? t : 0.f;
        o += t * Wm2[j];
    }
    out[g] = o + bm2[0];
}

// ============================== launch ==============================

extern "C" void kernel_launch(void* const* d_in, const int* in_sizes, int n_in,
                              void* d_out, int out_size, void* d_ws, size_t ws_size,
                              hipStream_t stream) {
    const float* x   = (const float*)d_in[0];
    const int*   ei  = (const int*)d_in[1];
    const float* ew  = (const float*)d_in[2];
    const int*   bvec= (const int*)d_in[3];
    const float* W1  = (const float*)d_in[4];
    const float* b1  = (const float*)d_in[5];
    const float* W2  = (const float*)d_in[6];
    const float* b2  = (const float*)d_in[7];
    const float* Wm1 = (const float*)d_in[8];
    const float* bm1 = (const float*)d_in[9];
    const float* Wm2 = (const float*)d_in[10];
    const float* bm2 = (const float*)d_in[11];
    float* out = (float*)d_out;

    const int E = in_sizes[2];
    const int N = in_sizes[3];
    const int G = out_size;
    const int* row = ei;
    const int* col = ei + E;
    const int nbuck = (N + BSZ - 1) >> BSH;   // 782 for N=100000

    char* p = (char*)d_ws;
    auto alloc = [&](size_t bytes) {
        void* r = (void*)p;
        p += (bytes + 255) & ~(size_t)255;
        return r;
    };

    unsigned long long* part = (unsigned long long*)alloc((size_t)E * 8);
    int2*  csr    = (int2*)alloc((size_t)E * 8);
    int*   cntB   = (int*)alloc((size_t)nbuck * 4);
    int*   base   = (int*)alloc((size_t)(nbuck + 1) * 4);
    int*   cursor = (int*)alloc((size_t)nbuck * 4);
    int*   row_ptr= (int*)alloc((size_t)(N + 1) * 4);
    float* dinv   = (float*)alloc((size_t)N * 4);
    float* hA     = (float*)alloc((size_t)N * DIMH * 4);
    float* hB     = (float*)alloc((size_t)N * DIMH * 4);
    float* sums   = (float*)alloc((size_t)(G * DIMH + G) * 4);
    float* cntG   = sums + G * DIMH;

    hipMemsetAsync(cntB, 0, (size_t)nbuck * 4, stream);
    hipMemsetAsync(sums, 0, (size_t)(G * DIMH + G) * 4, stream);

    const int PB = (E + EPB - 1) / EPB;

    // 1. partition + sort -> CSR, row_ptr, dinv
    k_hist<<<PB, 512, 0, stream>>>(col, cntB, E, nbuck);
    k_scan<<<1, 1024, 0, stream>>>(cntB, base, cursor, nbuck, E);
    k_scatter<<<PB, 512, 0, stream>>>(row, col, ew, cursor, part, E, nbuck);
    k_sortB<<<nbuck, 256, 0, stream>>>(part, base, csr, row_ptr, dinv, N, E);

    // 2. conv1
    k_gemm_s<128, DIMH><<<(N + 255) / 256, 256, 0, stream>>>(x, W1, dinv, hA, N);
    k_aggN<<<(N + 3) / 4, 256, 0, stream>>>(hA, row_ptr, csr, dinv, b1, hB, N);

    // 3. conv2
    k_gemm_s<DIMH, DIMH><<<(N + 255) / 256, 256, 0, stream>>>(hB, W2, dinv, hA, N);
    k_aggN<<<(N + 3) / 4, 256, 0, stream>>>(hA, row_ptr, csr, dinv, b2, hB, N);

    // 4. pool + head
    k_pool<<<(N + 255) / 256, 256, 0, stream>>>(hB, bvec, sums, cntG, N);
    k_mlp<<<1, 64, 0, stream>>>(sums, cntG, Wm1, bm1, Wm2, bm2, out, G);
}